// Round 3
// baseline (3416.436 us; speedup 1.0000x reference)
//
#include <hip/hip_runtime.h>
#include <math.h>

// ---------------------------------------------------------------------------
// QAT-LoRA GPT2 MLP (MI355X). Small-workspace design (~68.2 MB):
//   ws: amax[4] | t1 (8192x16 f32) | t2 (8192x16 f32) | qh (8192x8192 int8)
// fake_quant kept exact: quantized values are integer-valued bf16 (|q|<=127
// exact in bf16), bf16 MFMA accumulates integer products exactly in fp32;
// per-tensor scales applied in the epilogue. h = gelu(base+bias+lora) needs a
// global amax before quantization -> GEMM1 runs twice (pass A: amax only,
// pass B: writes int8 qh). t2 = h.A_proj^T is computed from dequantized qh
// (error ~1e-3, well under threshold).
// ---------------------------------------------------------------------------

typedef float  f32x4  __attribute__((ext_vector_type(4)));
typedef __bf16 bf16x8 __attribute__((ext_vector_type(8)));

__device__ __forceinline__ unsigned short quant_bf16(float v, float inv) {
  float q = rintf(v * inv);                    // round-half-even, matches jnp.round
  q = fminf(fmaxf(q, -127.f), 127.f);
  return (unsigned short)(__float_as_uint(q) >> 16);  // integer: exact bf16
}

// ---------------- absmax over fp32 tensor -> uint bits ----------------------
__global__ void absmax_k(const float* __restrict__ X, size_t n,
                         unsigned* __restrict__ out) {
  float m = 0.f;
  size_t i = ((size_t)blockIdx.x * blockDim.x + threadIdx.x) * 4;
  size_t stride = (size_t)gridDim.x * blockDim.x * 4;
  for (; i < n; i += stride) {
    float4 v = *(const float4*)&X[i];
    m = fmaxf(m, fmaxf(fmaxf(fabsf(v.x), fabsf(v.y)),
                       fmaxf(fabsf(v.z), fabsf(v.w))));
  }
#pragma unroll
  for (int off = 32; off; off >>= 1) m = fmaxf(m, __shfl_down(m, off));
  if ((threadIdx.x & 63) == 0) atomicMax(out, __float_as_uint(m));
}

// ---------------- T[m][r] = s * sum_d X[m][d] * A[r][d]   (r = 16) ----------
// XT=0: X fp32 (s=1).  XT=1: X int8, s = amax/127 (dequant folded at the end).
template <int XT>
__global__ __launch_bounds__(256) void lorat_k(const void* __restrict__ Xp,
                                               const float* __restrict__ A,
                                               float* __restrict__ T,
                                               int M, int K,
                                               const unsigned* __restrict__ aS) {
  __shared__ float Asl[16 * 512];  // 32 KB
  const int t  = threadIdx.x;
  const int c0 = blockIdx.y * 512;
  const int m0 = blockIdx.x * 128;
#pragma unroll
  for (int i = 0; i < 8; ++i) {
    int flat4 = i * 256 + t;
    int row = flat4 >> 7, col4 = flat4 & 127;
    *(float4*)&Asl[row * 512 + col4 * 4] =
        *(const float4*)&A[(size_t)row * K + c0 + col4 * 4];
  }
  __syncthreads();
  float s = 1.f;
  if constexpr (XT == 1) s = fmaxf(__uint_as_float(*aS) / 127.f, 1e-8f);
  const int kslot = t & 7;
  const int mg    = t >> 3;
  const int mrow  = m0 + mg * 4;
  float acc[4][16] = {};
  for (int it = 0; it < 16; ++it) {
    int d0 = it * 32 + kslot * 4;
    float4 xv[4];
#pragma unroll
    for (int rr = 0; rr < 4; ++rr) {
      if constexpr (XT == 0) {
        xv[rr] = *(const float4*)((const float*)Xp + (size_t)(mrow + rr) * K + c0 + d0);
      } else {
        char4 c = *(const char4*)((const signed char*)Xp + (size_t)(mrow + rr) * K + c0 + d0);
        xv[rr] = make_float4((float)c.x, (float)c.y, (float)c.z, (float)c.w);
      }
    }
#pragma unroll
    for (int r = 0; r < 16; ++r) {
      float4 a4 = *(const float4*)&Asl[r * 512 + d0];
#pragma unroll
      for (int rr = 0; rr < 4; ++rr)
        acc[rr][r] += xv[rr].x * a4.x + xv[rr].y * a4.y +
                      xv[rr].z * a4.z + xv[rr].w * a4.w;
    }
  }
#pragma unroll
  for (int rr = 0; rr < 4; ++rr)
#pragma unroll
    for (int r = 0; r < 16; ++r) {
      float v = acc[rr][r];
      v += __shfl_down(v, 1);
      v += __shfl_down(v, 2);
      v += __shfl_down(v, 4);
      acc[rr][r] = v;
    }
  if (kslot == 0) {
#pragma unroll
    for (int rr = 0; rr < 4; ++rr)
#pragma unroll
      for (int r = 0; r < 16; ++r)
        atomicAdd(&T[(size_t)(mrow + rr) * 16 + r], s * acc[rr][r]);
  }
}

// ---------------- fused-quant MFMA GEMM:  C[M][N] = fq(A)[M][K] . fq(B)[N][K]^T
// AQ: 0 = A is fp32, quantize in staging regs; 1 = A is int8 (convert to bf16)
// B is always fp32, quantized in staging regs.
// EPI: 1 = gelu + global amax only; 2 = gelu + quantize -> int8 Out; 3 = fp32 Out
template <int AQ, int EPI>
__global__ __launch_bounds__(256) void gemmQ(
    const void* __restrict__ Ap, const void* __restrict__ Bp,
    int M, int N, int K,
    const unsigned* __restrict__ aA, const unsigned* __restrict__ aB,
    const unsigned* __restrict__ aO,
    const float* __restrict__ bias, const float* __restrict__ Tl,
    const float* __restrict__ Bl, void* __restrict__ Outp,
    unsigned* __restrict__ amaxOut) {
  constexpr int LDK = 72;  // padded bf16 row stride: 144B -> 16B-aligned b128,
                           // 2-way (free) read conflicts instead of 16-way
  __shared__ __align__(16) unsigned short As[128 * LDK];  // 18 KB
  __shared__ __align__(16) unsigned short Bs[128 * LDK];  // 18 KB
  __shared__ float Ts[128 * 17];
  __shared__ float Bls[128 * 17];
  __shared__ float Bbs[128];

  const int t = threadIdx.x, lane = t & 63, w = t >> 6;
  const int wr = w >> 1, wc = w & 1;

  const int nbn = N / 128;
  const int q8  = gridDim.x >> 3;                 // grids here are %8 == 0
  const int wg  = (blockIdx.x & 7) * q8 + (blockIdx.x >> 3);
  const int bm = wg / nbn, bn = wg % nbn;

  const float sA   = fmaxf(__uint_as_float(*aA) / 127.f, 1e-8f);
  const float sB   = fmaxf(__uint_as_float(*aB) / 127.f, 1e-8f);
  const float invA = 1.f / sA, invB = 1.f / sB;

  const float*       Af = (const float*)Ap;
  const signed char* Ac = (const signed char*)Ap;
  const float*       Bf = (const float*)Bp;

  f32x4 acc[4][4] = {};
  float4 rA[8], rB[8];
  int4   rAi[2];

  const int nkt = K / 64;

  // ---- T14 async-stage split: global loads for tile kt+1 issue before the
  // MFMA phase of tile kt; their vmcnt-wait lands at the next ds_write. ----
#define LOADA(kt_)                                                             \
  if constexpr (AQ == 0) {                                                     \
    _Pragma("unroll") for (int i = 0; i < 8; ++i) {                            \
      int flat = i * 256 + t, row = flat >> 4, c4 = (flat & 15) * 4;           \
      rA[i] = *(const float4*)&Af[(size_t)(bm * 128 + row) * K + (kt_)*64 + c4];\
    }                                                                          \
  } else {                                                                     \
    _Pragma("unroll") for (int i = 0; i < 2; ++i) {                            \
      int flat = i * 256 + t, row = flat >> 2, cb = (flat & 3) * 16;           \
      rAi[i] = *(const int4*)&Ac[(size_t)(bm * 128 + row) * K + (kt_)*64 + cb];\
    }                                                                          \
  }
#define LOADB(kt_)                                                             \
  { _Pragma("unroll") for (int i = 0; i < 8; ++i) {                            \
      int flat = i * 256 + t, row = flat >> 4, c4 = (flat & 15) * 4;           \
      rB[i] = *(const float4*)&Bf[(size_t)(bn * 128 + row) * K + (kt_)*64 + c4];\
    } }

  LOADA(0);
  LOADB(0);

  for (int kt = 0; kt < nkt; ++kt) {
    // ---- write staged regs -> LDS (quantize / convert) ----
    if constexpr (AQ == 0) {
#pragma unroll
      for (int i = 0; i < 8; ++i) {
        int flat = i * 256 + t, row = flat >> 4, c4 = (flat & 15) * 4;
        ushort4 o;
        o.x = quant_bf16(rA[i].x, invA); o.y = quant_bf16(rA[i].y, invA);
        o.z = quant_bf16(rA[i].z, invA); o.w = quant_bf16(rA[i].w, invA);
        *(ushort4*)&As[row * LDK + c4] = o;
      }
    } else {
#pragma unroll
      for (int i = 0; i < 2; ++i) {
        int flat = i * 256 + t, row = flat >> 2, cb = (flat & 3) * 16;
        const signed char* pc = (const signed char*)&rAi[i];
#pragma unroll
        for (int g = 0; g < 4; ++g) {
          ushort4 o;
          o.x = (unsigned short)(__float_as_uint((float)pc[g * 4 + 0]) >> 16);
          o.y = (unsigned short)(__float_as_uint((float)pc[g * 4 + 1]) >> 16);
          o.z = (unsigned short)(__float_as_uint((float)pc[g * 4 + 2]) >> 16);
          o.w = (unsigned short)(__float_as_uint((float)pc[g * 4 + 3]) >> 16);
          *(ushort4*)&As[row * LDK + cb + g * 4] = o;
        }
      }
    }
#pragma unroll
    for (int i = 0; i < 8; ++i) {
      int flat = i * 256 + t, row = flat >> 4, c4 = (flat & 15) * 4;
      ushort4 o;
      o.x = quant_bf16(rB[i].x, invB); o.y = quant_bf16(rB[i].y, invB);
      o.z = quant_bf16(rB[i].z, invB); o.w = quant_bf16(rB[i].w, invB);
      *(ushort4*)&Bs[row * LDK + c4] = o;
    }
    if (kt + 1 < nkt) { LOADA(kt + 1); LOADB(kt + 1); }
    __syncthreads();
#pragma unroll
    for (int kk = 0; kk < 2; ++kk) {
      bf16x8 af[4], bfr[4];
#pragma unroll
      for (int m = 0; m < 4; ++m)
        af[m] = *reinterpret_cast<const bf16x8*>(
            &As[(wr * 64 + m * 16 + (lane & 15)) * LDK + kk * 32 + (lane >> 4) * 8]);
#pragma unroll
      for (int n = 0; n < 4; ++n)
        bfr[n] = *reinterpret_cast<const bf16x8*>(
            &Bs[(wc * 64 + n * 16 + (lane & 15)) * LDK + kk * 32 + (lane >> 4) * 8]);
#pragma unroll
      for (int m = 0; m < 4; ++m)
#pragma unroll
        for (int n = 0; n < 4; ++n)
          acc[m][n] = __builtin_amdgcn_mfma_f32_16x16x32_bf16(af[m], bfr[n],
                                                              acc[m][n], 0, 0, 0);
    }
    __syncthreads();
  }

  // ---- epilogue: stage lora operands + bias ----
#pragma unroll
  for (int i = 0; i < 2; ++i) {
    int flat = i * 256 + t;
    int row = flat >> 2, i4 = (flat & 3) * 4;
    float4 tv = *(const float4*)&Tl[(size_t)(bm * 128 + row) * 16 + i4];
    Ts[row * 17 + i4 + 0] = tv.x; Ts[row * 17 + i4 + 1] = tv.y;
    Ts[row * 17 + i4 + 2] = tv.z; Ts[row * 17 + i4 + 3] = tv.w;
    float4 bv = *(const float4*)&Bl[(size_t)(bn * 128 + row) * 16 + i4];
    Bls[row * 17 + i4 + 0] = bv.x; Bls[row * 17 + i4 + 1] = bv.y;
    Bls[row * 17 + i4 + 2] = bv.z; Bls[row * 17 + i4 + 3] = bv.w;
  }
  if (t < 32) *(float4*)&Bbs[t * 4] = *(const float4*)&bias[bn * 128 + t * 4];
  __syncthreads();

  const float s = sA * sB;
  float invO = 1.f;
  if constexpr (EPI == 2) invO = 1.f / fmaxf(__uint_as_float(*aO) / 127.f, 1e-8f);
  float lmax = 0.f;
#pragma unroll
  for (int m = 0; m < 4; ++m) {
#pragma unroll
    for (int n = 0; n < 4; ++n) {
#pragma unroll
      for (int j = 0; j < 4; ++j) {
        const int lr = wr * 64 + m * 16 + (lane >> 4) * 4 + j;
        const int lc = wc * 64 + n * 16 + (lane & 15);
        float lv = 0.f;
#pragma unroll
        for (int i = 0; i < 16; ++i) lv += Ts[lr * 17 + i] * Bls[lc * 17 + i];
        float v = acc[m][n][j] * s + Bbs[lc] + 2.0f * lv;
        const size_t g = (size_t)(bm * 128 + lr) * N + (bn * 128 + lc);
        if constexpr (EPI == 1) {
          float gl = 0.5f * v * (1.0f + erff(v * 0.70710678118654752f));
          lmax = fmaxf(lmax, fabsf(gl));
        } else if constexpr (EPI == 2) {
          float gl = 0.5f * v * (1.0f + erff(v * 0.70710678118654752f));
          float q = fminf(fmaxf(rintf(gl * invO), -127.f), 127.f);
          ((signed char*)Outp)[g] = (signed char)(int)q;
        } else {
          ((float*)Outp)[g] = v;
        }
      }
    }
  }
  if constexpr (EPI == 1) {
#pragma unroll
    for (int off = 32; off; off >>= 1) lmax = fmaxf(lmax, __shfl_down(lmax, off));
    if (lane == 0) atomicMax(amaxOut, __float_as_uint(lmax));
  }
#undef LOADA
#undef LOADB
}

// ---------------------------------------------------------------------------
extern "C" void kernel_launch(void* const* d_in, const int* in_sizes, int n_in,
                              void* d_out, int out_size, void* d_ws, size_t ws_size,
                              hipStream_t stream) {
  (void)in_sizes; (void)n_in; (void)out_size;
  const float* x      = (const float*)d_in[0];
  const float* w_fc   = (const float*)d_in[1];
  const float* b_fc   = (const float*)d_in[2];
  const float* A_fc   = (const float*)d_in[3];
  const float* B_fc   = (const float*)d_in[4];
  const float* w_proj = (const float*)d_in[5];
  const float* b_proj = (const float*)d_in[6];
  const float* A_proj = (const float*)d_in[7];
  const float* B_proj = (const float*)d_in[8];
  float* out = (float*)d_out;

  const int M = 8192, D = 2048, H = 8192;
  const size_t Ex  = (size_t)M * D;
  const size_t Ew1 = (size_t)H * D;
  const size_t Ew2 = (size_t)D * H;
  const size_t Eh  = (size_t)M * H;

  // ws: [0,16) amax{x,w_fc,w_proj,h} | t1 @256 | t2 @524544 | qh int8 @1048832
  const size_t NEED = 1048832 + Eh;  // ~68.2 MB
  if (ws_size < NEED) return;        // fail loudly as absmax error, not a fault
  char* ws = (char*)d_ws;
  unsigned* amax = (unsigned*)ws;
  float* t1 = (float*)(ws + 256);
  float* t2 = (float*)(ws + 524544);
  signed char* qh = (signed char*)(ws + 1048832);

  hipMemsetAsync(d_ws, 0, 1048832, stream);  // amax + t1 + t2 := 0

  absmax_k<<<2048, 256, 0, stream>>>(x, Ex, amax + 0);
  absmax_k<<<2048, 256, 0, stream>>>(w_fc, Ew1, amax + 1);
  absmax_k<<<2048, 256, 0, stream>>>(w_proj, Ew2, amax + 2);

  lorat_k<0><<<dim3(M / 128, D / 512), 256, 0, stream>>>(x, A_fc, t1, M, D, nullptr);

  // GEMM1 pass A: amax(h) only
  gemmQ<0, 1><<<(M / 128) * (H / 128), 256, 0, stream>>>(
      x, w_fc, M, H, D, amax + 0, amax + 1, amax + 3, b_fc, t1, B_fc,
      nullptr, amax + 3);
  // GEMM1 pass B: write int8 qh
  gemmQ<0, 2><<<(M / 128) * (H / 128), 256, 0, stream>>>(
      x, w_fc, M, H, D, amax + 0, amax + 1, amax + 3, b_fc, t1, B_fc,
      qh, nullptr);

  lorat_k<1><<<dim3(M / 128, H / 512), 256, 0, stream>>>(qh, A_proj, t2, M, H, amax + 3);

  // GEMM2: out = dq(qh).fq(w_proj)^T * s + b_proj + 2*t2.B_proj^T
  gemmQ<1, 3><<<(M / 128) * (D / 128), 256, 0, stream>>>(
      qh, w_proj, M, D, H, amax + 3, amax + 2, nullptr, b_proj, t2, B_proj,
      out, nullptr);
}